// Round 11
// baseline (471.627 us; speedup 1.0000x reference)
//
#include <hip/hip_runtime.h>
#include <hip/hip_bf16.h>
#include <cstdint>
#include <cstddef>

// NaryTreeLSTM bottom-up — 5-dispatch pipeline (R11):
//  1. setup: pack_weights + f32->bf16 convert + barrier clear (one launch)
//  2. leaves_gemm: leaves fused<3,1> (2048 blks) ∥ gemm_zx M=8191 (2048 blks)
//  3. fused_level3<4,3> l14
//  4. fused_level3<4,3> l13
//  5. tail: levels 12..0 (big phase l12..l8 @64 blocks, small l7..l0 @16)
//
// R11 theory: pre-tail wall time (~289us) >> modeled kernel time (~85us) —
// per-dispatch fixed overhead ~15-25us dominates; cut dispatches 9 -> 5.
//
// Hard-won constraints:
//  * R2/R5: tail job needs ~180 VGPRs. 1024-thread blocks (VGPR cap 64) and
//    min-occupancy launch bounds (cap 128) cause scratch spills (WRITE_SIZE
//    3MB->40-53MB, 2-3x slower). 256-thread blocks, plain bounds ONLY.
//  * R3/R4/R9: barrier cost = population term + big fixed term (agent fence);
//    flat arrival at <=64 pop; hierarchical only pays at 256.
//  * R3/R8: XOR swizzle (both-sides) kills LDS bank conflicts.
//  * R7: zero-LDS fused levels failed — B must be LDS-reused.
//  * R9: folding cvt into A-staging serializes vs global_load_lds — keep
//    the separate convert (now merged into setup, not into staging).
//
// Wpack[12][256][256] bf16: mats {Wi,Wo,Wu,Wf, Ui0,Uo0,Uu0,Uf0, Ui1,Uo1,Uu1,Uf1}
// biasv[4][256] fp32. h stored bf16, c fp32.
// f gates: f_l = sig(Wf x + bF + Uf0 h_l), f_r = sig(Wf x + bF + Uf1 h_r).

typedef __attribute__((ext_vector_type(8))) __bf16 bf16x8;
typedef __attribute__((ext_vector_type(4))) float floatx4;

#define TB 64   // tail grid: 16 d-tiles x 4 m-groups

__device__ __forceinline__ float sigf(float x) { return 1.0f / (1.0f + __expf(-x)); }

__device__ __forceinline__ void load_lds16(const void* g, void* l) {
    __builtin_amdgcn_global_load_lds(
        (const __attribute__((address_space(1))) unsigned int*)g,
        (__attribute__((address_space(3))) unsigned int*)l, 16, 0, 0);
}

// ---- setup: pack weights + convert emb + clear barriers (one launch) -----
#define NB_PACK 3072                 // 12 mats x 256 d-rows
#define NB_CONV 16385                // ceil(65535*256/4 / 256)
__global__ void setup(const float* __restrict__ Wi, const float* __restrict__ bi, const float* __restrict__ Ui,
                      const float* __restrict__ Wo, const float* __restrict__ bo, const float* __restrict__ Uo,
                      const float* __restrict__ Wu, const float* __restrict__ bu, const float* __restrict__ Uu,
                      const float* __restrict__ Wf, const float* __restrict__ bf, const float* __restrict__ Uf,
                      __hip_bfloat16* __restrict__ Wpack, float* __restrict__ biasv,
                      const float* __restrict__ emb, __hip_bfloat16* __restrict__ embB,
                      unsigned* __restrict__ bar)
{
    const int bid = blockIdx.x;
    const int t = threadIdx.x;
    if (bid < NB_PACK) {
        int m = bid >> 8, d = bid & 255, k = t;
        const float* tbl[12] = {Wi, Wo, Wu, Wf,
                                Ui, Uo, Uu, Uf,
                                Ui + 65536, Uo + 65536, Uu + 65536, Uf + 65536};
        Wpack[((size_t)m * 256 + d) * 256 + k] = __float2bfloat16(tbl[m][d * 256 + k]);
        if (m < 4 && k == 0) {
            const float* bt[4] = {bi, bo, bu, bf};
            biasv[m * 256 + d] = bt[m][d];
        }
    } else if (bid < NB_PACK + NB_CONV) {
        int i = (bid - NB_PACK) * 256 + t;
        if (i < 65535 * 256 / 4) {
            float4 v = ((const float4*)emb)[i];
            __hip_bfloat16 tmp[4];
            tmp[0] = __float2bfloat16(v.x);
            tmp[1] = __float2bfloat16(v.y);
            tmp[2] = __float2bfloat16(v.z);
            tmp[3] = __float2bfloat16(v.w);
            *(ushort4*)(embB + (size_t)i * 4) = *(const ushort4*)tmp;
        }
    } else {
        bar[t] = 0;   // 256 uints = 1 KB
    }
}

// ---- shared bodies -------------------------------------------------------
// fused level body (R8-proven): BK=64, XOR-swizzled sA/sB, zero conflicts.
template<int NS, int NP>
__device__ __forceinline__ void fused_body(
    __hip_bfloat16* sA, __hip_bfloat16* sB,
    int dchunk, int bm0,
    const __hip_bfloat16* __restrict__ embX,
    const __hip_bfloat16* __restrict__ hprev,
    const float* __restrict__ cprev,
    const __hip_bfloat16* __restrict__ Wpack,
    const float* __restrict__ biasv,
    __hip_bfloat16* __restrict__ hout,
    float* __restrict__ cout,
    int M)
{
    const int t = threadIdx.x;
    const int lane = t & 63;
    const int w = t >> 6;
    const int lrow = lane & 15;
    const int q = lane >> 4;

    floatx4 accS[3][4];
    floatx4 accF[NP][4];
    #pragma unroll
    for (int s = 0; s < 3; ++s)
        #pragma unroll
        for (int mt = 0; mt < 4; ++mt) accS[s][mt] = (floatx4){0.f, 0.f, 0.f, 0.f};
    #pragma unroll
    for (int p = 0; p < NP; ++p)
        #pragma unroll
        for (int mt = 0; mt < 4; ++mt) accF[p][mt] = (floatx4){0.f, 0.f, 0.f, 0.f};

    #pragma unroll
    for (int p = 0; p < NP; ++p) {
        const __hip_bfloat16* Abase = (p == 0) ? embX : hprev;
        const int astride = (p == 0) ? 256 : 512;
        const int aoff = (p == 0) ? 0 : (p - 1) * 256;
        for (int kk = 0; kk < 4; ++kk) {
            const int k0 = kk * 64;
            #pragma unroll
            for (int rep = 0; rep < 2; ++rep) {
                int C = rep * 256 + t;
                int r = C >> 3, c0 = C & 7;
                load_lds16(Abase + (size_t)(bm0 + r) * astride + aoff + k0 + (c0 ^ (r & 7)) * 8,
                           &sA[C * 8]);
            }
            #pragma unroll
            for (int rep = 0; rep < NS * 2; ++rep) {
                int C = rep * 256 + t;
                int s = C >> 9, r = (C >> 3) & 63, c0 = C & 7;
                load_lds16(Wpack + (size_t)((p * 4 + s) * 256 + dchunk * 64 + r) * 256
                                 + k0 + (c0 ^ (r & 7)) * 8,
                           &sB[C * 8]);
            }
            __syncthreads();

            bf16x8 af[2][4];
            #pragma unroll
            for (int ks = 0; ks < 2; ++ks)
                #pragma unroll
                for (int mt = 0; mt < 4; ++mt)
                    af[ks][mt] = *(const bf16x8*)&sA[(mt * 16 + lrow) * 64
                                                     + (((ks * 4 + q) ^ (lrow & 7)) * 8)];
            #pragma unroll
            for (int s = 0; s < NS; ++s) {
                #pragma unroll
                for (int ks = 0; ks < 2; ++ks) {
                    bf16x8 bfr = *(const bf16x8*)&sB[(s * 64 + w * 16 + lrow) * 64
                                                     + (((ks * 4 + q) ^ (lrow & 7)) * 8)];
                    if (s < 3) {
                        #pragma unroll
                        for (int mt = 0; mt < 4; ++mt)
                            accS[s][mt] = __builtin_amdgcn_mfma_f32_16x16x32_bf16(af[ks][mt], bfr, accS[s][mt], 0, 0, 0);
                    } else {
                        #pragma unroll
                        for (int mt = 0; mt < 4; ++mt)
                            accF[p][mt] = __builtin_amdgcn_mfma_f32_16x16x32_bf16(af[ks][mt], bfr, accF[p][mt], 0, 0, 0);
                    }
                }
            }
            __syncthreads();
        }
    }

    const int d = dchunk * 64 + w * 16 + lrow;
    const float bI = biasv[d];
    const float bO = biasv[256 + d];
    const float bU = biasv[512 + d];
    const float bF = (NS == 4) ? biasv[768 + d] : 0.0f;
    #pragma unroll
    for (int mt = 0; mt < 4; ++mt) {
        #pragma unroll
        for (int rr = 0; rr < 4; ++rr) {
            const int m = bm0 + mt * 16 + q * 4 + rr;
            if (m >= M) continue;
            float iv = sigf(accS[0][mt][rr] + bI);
            float ov = sigf(accS[1][mt][rr] + bO);
            float uv = tanhf(accS[2][mt][rr] + bU);
            float c;
            if (NS == 4) {
                float fx = accF[0][mt][rr];
                float fl = sigf(fx + accF[NP >= 2 ? 1 : 0][mt][rr] + bF);
                float fr = sigf(fx + accF[NP >= 3 ? 2 : 0][mt][rr] + bF);
                c = iv * uv + fl * cprev[(size_t)m * 512 + d]
                            + fr * cprev[(size_t)m * 512 + 256 + d];
            } else {
                c = iv * uv;
            }
            cout[(size_t)m * 256 + d] = c;
            hout[(size_t)m * 256 + d] = __float2bfloat16(ov * tanhf(c));
        }
    }
}

// gemm_zx body: preZ[m][s*256+d] = embB[m] . Wpack[s][d] + biasv[s][d]
__device__ __forceinline__ void gemm_body(
    __hip_bfloat16* sA, __hip_bfloat16* sB,
    int s, int d0, int bm0,
    const __hip_bfloat16* __restrict__ embB,
    const __hip_bfloat16* __restrict__ Wpack,
    const float* __restrict__ biasv,
    float* __restrict__ preZ,
    int M)
{
    const int t = threadIdx.x;
    const int lane = t & 63, w = t >> 6, lrow = lane & 15, q = lane >> 4;

    floatx4 acc[4];
    #pragma unroll
    for (int mt = 0; mt < 4; ++mt) acc[mt] = (floatx4){0.f, 0.f, 0.f, 0.f};

    for (int kk = 0; kk < 8; ++kk) {
        const int k0 = kk * 32;
        {
            int r = t >> 2, kc = t & 3;
            load_lds16(embB + (size_t)(bm0 + r) * 256 + k0 + kc * 8, &sA[t * 8]);
            load_lds16(Wpack + (size_t)(s * 256 + d0 + r) * 256 + k0 + kc * 8, &sB[t * 8]);
        }
        __syncthreads();
        bf16x8 af[4];
        #pragma unroll
        for (int mt = 0; mt < 4; ++mt)
            af[mt] = *(const bf16x8*)&sA[(mt * 16 + lrow) * 32 + q * 8];
        bf16x8 bfr = *(const bf16x8*)&sB[(w * 16 + lrow) * 32 + q * 8];
        #pragma unroll
        for (int mt = 0; mt < 4; ++mt)
            acc[mt] = __builtin_amdgcn_mfma_f32_16x16x32_bf16(af[mt], bfr, acc[mt], 0, 0, 0);
        __syncthreads();
    }

    const int d = d0 + w * 16 + lrow;
    const float bv = biasv[s * 256 + d];
    #pragma unroll
    for (int mt = 0; mt < 4; ++mt)
        #pragma unroll
        for (int rr = 0; rr < 4; ++rr) {
            int m = bm0 + mt * 16 + q * 4 + rr;
            if (m < M) preZ[(size_t)m * 1024 + s * 256 + d] = acc[mt][rr] + bv;
        }
}

// ---- launch 2: leaves (2048 blocks) + gemm_zx M=8191 (2048 blocks) -------
__global__ __launch_bounds__(256) void leaves_gemm(
    const __hip_bfloat16* __restrict__ embB,
    const __hip_bfloat16* __restrict__ Wpack,
    const float* __restrict__ biasv,
    float* __restrict__ preZ,
    __hip_bfloat16* __restrict__ hbuf,
    float* __restrict__ cbuf)
{
    __shared__ __hip_bfloat16 smem[16384];   // 32 KB
    const int bid = blockIdx.x;
    if (bid < 2048) {
        // Leaves: level 15, n = 32768, start = 32767. NS=3, NP=1.
        const int n = 32768, start = n - 1;
        fused_body<3, 1>(smem, smem + 4096,
                         bid & 3, (bid >> 2) * 64,
                         embB + (size_t)start * 256, nullptr, nullptr,
                         Wpack, biasv,
                         hbuf + (size_t)start * 256, cbuf + (size_t)start * 256, n);
    } else {
        // gemm_zx for tail nodes 0..8190 (levels 12..0).
        const int gid = bid - 2048;
        const int x = gid & 15;          // s*4 + d-block
        gemm_body(smem, smem + 2048,
                  x >> 2, (x & 3) * 64, (gid >> 4) * 64,
                  embB, Wpack, biasv, preZ, 8191);
    }
}

// ---- launches 3,4: big internal levels (l14, l13) ------------------------
template<int NS, int NP>
__global__ __launch_bounds__(256) void fused_level3(
    const __hip_bfloat16* __restrict__ embX,
    const __hip_bfloat16* __restrict__ hprev,
    const float* __restrict__ cprev,
    const __hip_bfloat16* __restrict__ Wpack,
    const float* __restrict__ biasv,
    __hip_bfloat16* __restrict__ hout,
    float* __restrict__ cout,
    int M)
{
    __shared__ __hip_bfloat16 sA[64 * 64];
    __shared__ __hip_bfloat16 sB[NS * 64 * 64];
    fused_body<NS, NP>(sA, sB, blockIdx.x, blockIdx.y * 64,
                       embX, hprev, cprev, Wpack, biasv, hout, cout, M);
}

// ---- tail: levels 12..0, 64 blocks x 256 threads -------------------------
// dt = bid&15 (d-tile), g = bid>>4 (m-group 0..3); big phase (l>7): 16
// wave-slots per d-tile (slot = g*4+w, stride 16), flat 64-count barrier.
// Levels 7..0: only g==0 blocks survive (slot = w, stride 4), 16-count
// barrier. sB XOR-swizzle both-sides (R3-proven).
__global__ __launch_bounds__(256) void tail_levels(
    __hip_bfloat16* __restrict__ hbuf, float* __restrict__ cbuf,
    const __hip_bfloat16* __restrict__ Wpack,
    const float* __restrict__ preZ,
    unsigned* __restrict__ bar, float* __restrict__ out)
{
    __shared__ __hip_bfloat16 sB[8 * 16 * 256];   // 64 KB: U mats for this d-tile
    const int bid = blockIdx.x;
    const int t = threadIdx.x;
    const int dt = bid & 15;     // d-tile
    const int g = bid >> 4;      // m-group 0..3
    const int w = t >> 6, lane = t & 63, lrow = lane & 15, q = lane >> 4;

    // Stage U mats 4..11, rows dt*16..+16, once (survives inter-level fences).
    for (int rnd = 0; rnd < 16; ++rnd) {
        int C = rnd * 256 + t;               // physical chunk 0..4095
        int q8k = C & 31, r = (C >> 5) & 15, m8 = C >> 9;
        load_lds16(Wpack + (size_t)((4 + m8) * 256 + dt * 16 + r) * 256 + (q8k ^ (r & 7)) * 8,
                   &sB[(size_t)C * 8]);
    }
    __syncthreads();

    const int d = dt * 16 + lrow;
    unsigned barnum = 0;   // big (64-count) barrier generation
    unsigned snum = 0;     // small (16-count) barrier generation

    for (int l = 12; l >= 0; --l) {
        if (l <= 7 && g != 0) break;   // 48 blocks exit after the l=8 barrier

        const int n = 1 << l;
        const int start = n - 1;
        const int startc = 2 * n - 1;
        const __hip_bfloat16* hp = hbuf + (size_t)startc * 256;
        const float* cp = cbuf + (size_t)startc * 256;
        __hip_bfloat16* ho = hbuf + (size_t)start * 256;
        float* co = cbuf + (size_t)start * 256;
        const int nmt = (n + 15) >> 4;
        const int slot   = (l > 7) ? (g * 4 + w) : w;
        const int stride = (l > 7) ? 16 : 4;

        for (int mt = slot; mt < nmt; mt += stride) {
            const int m0 = mt * 16;
            // Preload A fragments (children h): 16 independent loads.
            bf16x8 af[2][8];
            #pragma unroll
            for (int p = 0; p < 2; ++p)
                #pragma unroll
                for (int kk = 0; kk < 8; ++kk)
                    af[p][kk] = *(const bf16x8*)(hp + (size_t)(m0 + lrow) * 512 + p * 256 + kk * 32 + q * 8);
            // Preload z (bias folded) and child c.
            float zi[4][4], clr[2][4];
            #pragma unroll
            for (int rr = 0; rr < 4; ++rr) {
                int m = m0 + q * 4 + rr;
                #pragma unroll
                for (int s = 0; s < 4; ++s)
                    zi[s][rr] = preZ[(size_t)(start + m) * 1024 + s * 256 + d];
                clr[0][rr] = cp[(size_t)m * 512 + d];
                clr[1][rr] = cp[(size_t)m * 512 + 256 + d];
            }

            floatx4 accS[3], accF1, accF2;
            #pragma unroll
            for (int s = 0; s < 3; ++s)
                accS[s] = (floatx4){zi[s][0], zi[s][1], zi[s][2], zi[s][3]};
            accF1 = (floatx4){0.f, 0.f, 0.f, 0.f};
            accF2 = (floatx4){0.f, 0.f, 0.f, 0.f};

            #pragma unroll
            for (int p = 0; p < 2; ++p)
                #pragma unroll
                for (int kk = 0; kk < 8; ++kk)
                    #pragma unroll
                    for (int s = 0; s < 4; ++s) {
                        bf16x8 bfr = *(const bf16x8*)&sB[((p * 4 + s) * 16 + lrow) * 256
                                                         + (((kk * 4 + q) ^ (lrow & 7)) * 8)];
                        if (s < 3)
                            accS[s] = __builtin_amdgcn_mfma_f32_16x16x32_bf16(af[p][kk], bfr, accS[s], 0, 0, 0);
                        else if (p == 0)
                            accF1 = __builtin_amdgcn_mfma_f32_16x16x32_bf16(af[p][kk], bfr, accF1, 0, 0, 0);
                        else
                            accF2 = __builtin_amdgcn_mfma_f32_16x16x32_bf16(af[p][kk], bfr, accF2, 0, 0, 0);
                    }

            #pragma unroll
            for (int rr = 0; rr < 4; ++rr) {
                int m = m0 + q * 4 + rr;
                if (m >= n) continue;
                float iv = sigf(accS[0][rr]);
                float ov = sigf(accS[1][rr]);
                float uv = tanhf(accS[2][rr]);
                float fx = zi[3][rr];
                float fl = sigf(fx + accF1[rr]);
                float fr = sigf(fx + accF2[rr]);
                float c = iv * uv + fl * clr[0][rr] + fr * clr[1][rr];
                float hv = ov * tanhf(c);
                if (l == 0) {
                    out[d] = hv;           // root h, fp32
                    out[256 + d] = c;      // root c
                } else {
                    co[(size_t)m * 256 + d] = c;
                    ho[(size_t)m * 256 + d] = __float2bfloat16(hv);
                }
            }
        }

        if (l > 0) {
            __syncthreads();
            if (l > 7) {
                // Flat 64-count barrier (levels 12..8).
                ++barnum;
                if (t == 0) {
                    unsigned v = __hip_atomic_fetch_add(&bar[0], 1, __ATOMIC_ACQ_REL,
                                                        __HIP_MEMORY_SCOPE_AGENT) + 1;
                    if (v == barnum * 64u) {
                        __hip_atomic_fetch_add(&bar[64], 1, __ATOMIC_RELEASE,
                                               __HIP_MEMORY_SCOPE_AGENT);
                    } else {
                        while (__hip_atomic_load(&bar[64], __ATOMIC_RELAXED,
                                                 __HIP_MEMORY_SCOPE_AGENT) < barnum)
                            __builtin_amdgcn_s_sleep(1);
                    }
                }
            } else {
                // Flat 16-count barrier (levels 7..1, survivors only).
                ++snum;
                if (t == 0) {
                    unsigned v = __hip_atomic_fetch_add(&bar[128], 1, __ATOMIC_ACQ_REL,
                                                        __HIP_MEMORY_SCOPE_AGENT) + 1;
                    if (v == snum * 16u) {
                        __hip_atomic_fetch_add(&bar[192], 1, __ATOMIC_RELEASE,
                                               __HIP_MEMORY_SCOPE_AGENT);
                    } else {
                        while (__hip_atomic_load(&bar[192], __ATOMIC_RELAXED,
                                                 __HIP_MEMORY_SCOPE_AGENT) < snum)
                            __builtin_amdgcn_s_sleep(1);
                    }
                }
            }
            __syncthreads();
            __builtin_amdgcn_fence(__ATOMIC_ACQUIRE, "agent");
        }
    }
}

extern "C" void kernel_launch(void* const* d_in, const int* in_sizes, int n_in,
                              void* d_out, int out_size, void* d_ws, size_t ws_size,
                              hipStream_t stream)
{
    const float* emb = (const float*)d_in[0];
    const float* Wi  = (const float*)d_in[1];
    const float* bi  = (const float*)d_in[2];
    const float* Ui  = (const float*)d_in[3];
    const float* Wo  = (const float*)d_in[4];
    const float* bo  = (const float*)d_in[5];
    const float* Uo  = (const float*)d_in[6];
    const float* Wu  = (const float*)d_in[7];
    const float* bu  = (const float*)d_in[8];
    const float* Uu  = (const float*)d_in[9];
    const float* Wf  = (const float*)d_in[10];
    const float* bf  = (const float*)d_in[11];
    const float* Uf  = (const float*)d_in[12];

    char* p = (char*)d_ws;
    __hip_bfloat16* Wpack = (__hip_bfloat16*)p;  p += (size_t)12 * 256 * 256 * 2;
    float* biasv          = (float*)p;           p += (size_t)4 * 256 * 4;
    __hip_bfloat16* embB  = (__hip_bfloat16*)p;  p += (size_t)65535 * 256 * 2;
    __hip_bfloat16* hbuf  = (__hip_bfloat16*)p;  p += (size_t)65535 * 256 * 2;
    float* cbuf           = (float*)p;           p += (size_t)65535 * 256 * 4;
    float* preZ           = (float*)p;           p += (size_t)8191 * 1024 * 4;
    unsigned* bar         = (unsigned*)p;        p += 1024;

    // 1. setup: pack + convert + bar clear.
    setup<<<NB_PACK + NB_CONV + 1, 256, 0, stream>>>(
        Wi, bi, Ui, Wo, bo, Uo, Wu, bu, Uu, Wf, bf, Uf,
        Wpack, biasv, emb, embB, bar);

    // 2. leaves (n=32768) + gemm_zx (preZ for nodes 0..8190).
    leaves_gemm<<<4096, 256, 0, stream>>>(embB, Wpack, biasv, preZ, hbuf, cbuf);

    // 3,4. big internal levels 14, 13.
    for (int l = 14; l >= 13; --l) {
        const int n = 1 << l;
        const int start = n - 1;
        const int startc = 2 * n - 1;
        fused_level3<4, 3><<<dim3(4, n / 64), 256, 0, stream>>>(
            embB + (size_t)start * 256,
            hbuf + (size_t)startc * 256,
            cbuf + (size_t)startc * 256,
            Wpack, biasv,
            hbuf + (size_t)start * 256, cbuf + (size_t)start * 256, n);
    }

    // 5. tail: levels 12..0; writes root h,c to out directly.
    tail_levels<<<TB, 256, 0, stream>>>(hbuf, cbuf, Wpack, preZ, bar, (float*)d_out);
}

// Round 12
// 398.696 us; speedup vs baseline: 1.1829x; 1.1829x over previous
//
#include <hip/hip_runtime.h>
#include <hip/hip_bf16.h>
#include <cstdint>
#include <cstddef>

// NaryTreeLSTM bottom-up — 7-dispatch pipeline (R12):
//  1. setup: pack_weights + f32->bf16 convert + barrier clear (one launch)
//  2. leaves_gemm: leaves fused<3,1> (2048 blks) ∥ gemm_zx M=2047 (512 blks)
//  3-6. fused_level3<4,3> l14..l11
//  7. tail: levels 10..0 (R10-proven: big l10..l8 @64 blocks, small l7..l0 @16)
//
// R11 lesson: moving l12/l11 into the tail (16 jobs/slot serial, 64-block
// executor) cost +122us while saving only ~45us of dispatches — the tail
// executor is only right when jobs/slot is small. Dispatch overhead ~10us
// each; the setup & leaves∥gemm merges are kept (parallelism-preserving).
//
// Hard-won constraints:
//  * R2/R5: tail job needs ~180 VGPRs. 1024-thread blocks (VGPR cap 64) and
//    min-occupancy launch bounds (cap 128) cause scratch spills. 256-thread
//    blocks, plain __launch_bounds__(256) ONLY.
//  * R3/R4/R9: barrier cost = population term + big fixed term (agent fence);
//    flat arrival at <=64 pop; hierarchical only pays at 256.
//  * R3/R8: XOR swizzle (both-sides) kills LDS bank conflicts.
//  * R7: zero-LDS fused levels failed — B must be LDS-reused.
//  * R9: folding cvt into A-staging serializes vs global_load_lds — keep
//    the separate convert (merged into setup, not into staging).
//
// Wpack[12][256][256] bf16: mats {Wi,Wo,Wu,Wf, Ui0,Uo0,Uu0,Uf0, Ui1,Uo1,Uu1,Uf1}
// biasv[4][256] fp32. h stored bf16, c fp32.
// f gates: f_l = sig(Wf x + bF + Uf0 h_l), f_r = sig(Wf x + bF + Uf1 h_r).

typedef __attribute__((ext_vector_type(8))) __bf16 bf16x8;
typedef __attribute__((ext_vector_type(4))) float floatx4;

#define TB 64   // tail grid: 16 d-tiles x 4 m-groups

__device__ __forceinline__ float sigf(float x) { return 1.0f / (1.0f + __expf(-x)); }

__device__ __forceinline__ void load_lds16(const void* g, void* l) {
    __builtin_amdgcn_global_load_lds(
        (const __attribute__((address_space(1))) unsigned int*)g,
        (__attribute__((address_space(3))) unsigned int*)l, 16, 0, 0);
}

// ---- setup: pack weights + convert emb + clear barriers (one launch) -----
#define NB_PACK 3072                 // 12 mats x 256 d-rows
#define NB_CONV 16385                // ceil(65535*256/4 / 256)
__global__ void setup(const float* __restrict__ Wi, const float* __restrict__ bi, const float* __restrict__ Ui,
                      const float* __restrict__ Wo, const float* __restrict__ bo, const float* __restrict__ Uo,
                      const float* __restrict__ Wu, const float* __restrict__ bu, const float* __restrict__ Uu,
                      const float* __restrict__ Wf, const float* __restrict__ bf, const float* __restrict__ Uf,
                      __hip_bfloat16* __restrict__ Wpack, float* __restrict__ biasv,
                      const float* __restrict__ emb, __hip_bfloat16* __restrict__ embB,
                      unsigned* __restrict__ bar)
{
    const int bid = blockIdx.x;
    const int t = threadIdx.x;
    if (bid < NB_PACK) {
        int m = bid >> 8, d = bid & 255, k = t;
        const float* tbl[12] = {Wi, Wo, Wu, Wf,
                                Ui, Uo, Uu, Uf,
                                Ui + 65536, Uo + 65536, Uu + 65536, Uf + 65536};
        Wpack[((size_t)m * 256 + d) * 256 + k] = __float2bfloat16(tbl[m][d * 256 + k]);
        if (m < 4 && k == 0) {
            const float* bt[4] = {bi, bo, bu, bf};
            biasv[m * 256 + d] = bt[m][d];
        }
    } else if (bid < NB_PACK + NB_CONV) {
        int i = (bid - NB_PACK) * 256 + t;
        if (i < 65535 * 256 / 4) {
            float4 v = ((const float4*)emb)[i];
            __hip_bfloat16 tmp[4];
            tmp[0] = __float2bfloat16(v.x);
            tmp[1] = __float2bfloat16(v.y);
            tmp[2] = __float2bfloat16(v.z);
            tmp[3] = __float2bfloat16(v.w);
            *(ushort4*)(embB + (size_t)i * 4) = *(const ushort4*)tmp;
        }
    } else {
        bar[t] = 0;   // 256 uints = 1 KB
    }
}

// ---- shared bodies -------------------------------------------------------
// fused level body (R8-proven): BK=64, XOR-swizzled sA/sB, zero conflicts.
template<int NS, int NP>
__device__ __forceinline__ void fused_body(
    __hip_bfloat16* sA, __hip_bfloat16* sB,
    int dchunk, int bm0,
    const __hip_bfloat16* __restrict__ embX,
    const __hip_bfloat16* __restrict__ hprev,
    const float* __restrict__ cprev,
    const __hip_bfloat16* __restrict__ Wpack,
    const float* __restrict__ biasv,
    __hip_bfloat16* __restrict__ hout,
    float* __restrict__ cout,
    int M)
{
    const int t = threadIdx.x;
    const int lane = t & 63;
    const int w = t >> 6;
    const int lrow = lane & 15;
    const int q = lane >> 4;

    floatx4 accS[3][4];
    floatx4 accF[NP][4];
    #pragma unroll
    for (int s = 0; s < 3; ++s)
        #pragma unroll
        for (int mt = 0; mt < 4; ++mt) accS[s][mt] = (floatx4){0.f, 0.f, 0.f, 0.f};
    #pragma unroll
    for (int p = 0; p < NP; ++p)
        #pragma unroll
        for (int mt = 0; mt < 4; ++mt) accF[p][mt] = (floatx4){0.f, 0.f, 0.f, 0.f};

    #pragma unroll
    for (int p = 0; p < NP; ++p) {
        const __hip_bfloat16* Abase = (p == 0) ? embX : hprev;
        const int astride = (p == 0) ? 256 : 512;
        const int aoff = (p == 0) ? 0 : (p - 1) * 256;
        for (int kk = 0; kk < 4; ++kk) {
            const int k0 = kk * 64;
            #pragma unroll
            for (int rep = 0; rep < 2; ++rep) {
                int C = rep * 256 + t;
                int r = C >> 3, c0 = C & 7;
                load_lds16(Abase + (size_t)(bm0 + r) * astride + aoff + k0 + (c0 ^ (r & 7)) * 8,
                           &sA[C * 8]);
            }
            #pragma unroll
            for (int rep = 0; rep < NS * 2; ++rep) {
                int C = rep * 256 + t;
                int s = C >> 9, r = (C >> 3) & 63, c0 = C & 7;
                load_lds16(Wpack + (size_t)((p * 4 + s) * 256 + dchunk * 64 + r) * 256
                                 + k0 + (c0 ^ (r & 7)) * 8,
                           &sB[C * 8]);
            }
            __syncthreads();

            bf16x8 af[2][4];
            #pragma unroll
            for (int ks = 0; ks < 2; ++ks)
                #pragma unroll
                for (int mt = 0; mt < 4; ++mt)
                    af[ks][mt] = *(const bf16x8*)&sA[(mt * 16 + lrow) * 64
                                                     + (((ks * 4 + q) ^ (lrow & 7)) * 8)];
            #pragma unroll
            for (int s = 0; s < NS; ++s) {
                #pragma unroll
                for (int ks = 0; ks < 2; ++ks) {
                    bf16x8 bfr = *(const bf16x8*)&sB[(s * 64 + w * 16 + lrow) * 64
                                                     + (((ks * 4 + q) ^ (lrow & 7)) * 8)];
                    if (s < 3) {
                        #pragma unroll
                        for (int mt = 0; mt < 4; ++mt)
                            accS[s][mt] = __builtin_amdgcn_mfma_f32_16x16x32_bf16(af[ks][mt], bfr, accS[s][mt], 0, 0, 0);
                    } else {
                        #pragma unroll
                        for (int mt = 0; mt < 4; ++mt)
                            accF[p][mt] = __builtin_amdgcn_mfma_f32_16x16x32_bf16(af[ks][mt], bfr, accF[p][mt], 0, 0, 0);
                    }
                }
            }
            __syncthreads();
        }
    }

    const int d = dchunk * 64 + w * 16 + lrow;
    const float bI = biasv[d];
    const float bO = biasv[256 + d];
    const float bU = biasv[512 + d];
    const float bF = (NS == 4) ? biasv[768 + d] : 0.0f;
    #pragma unroll
    for (int mt = 0; mt < 4; ++mt) {
        #pragma unroll
        for (int rr = 0; rr < 4; ++rr) {
            const int m = bm0 + mt * 16 + q * 4 + rr;
            if (m >= M) continue;
            float iv = sigf(accS[0][mt][rr] + bI);
            float ov = sigf(accS[1][mt][rr] + bO);
            float uv = tanhf(accS[2][mt][rr] + bU);
            float c;
            if (NS == 4) {
                float fx = accF[0][mt][rr];
                float fl = sigf(fx + accF[NP >= 2 ? 1 : 0][mt][rr] + bF);
                float fr = sigf(fx + accF[NP >= 3 ? 2 : 0][mt][rr] + bF);
                c = iv * uv + fl * cprev[(size_t)m * 512 + d]
                            + fr * cprev[(size_t)m * 512 + 256 + d];
            } else {
                c = iv * uv;
            }
            cout[(size_t)m * 256 + d] = c;
            hout[(size_t)m * 256 + d] = __float2bfloat16(ov * tanhf(c));
        }
    }
}

// gemm_zx body: preZ[m][s*256+d] = embB[m] . Wpack[s][d] + biasv[s][d]
__device__ __forceinline__ void gemm_body(
    __hip_bfloat16* sA, __hip_bfloat16* sB,
    int s, int d0, int bm0,
    const __hip_bfloat16* __restrict__ embB,
    const __hip_bfloat16* __restrict__ Wpack,
    const float* __restrict__ biasv,
    float* __restrict__ preZ,
    int M)
{
    const int t = threadIdx.x;
    const int lane = t & 63, w = t >> 6, lrow = lane & 15, q = lane >> 4;

    floatx4 acc[4];
    #pragma unroll
    for (int mt = 0; mt < 4; ++mt) acc[mt] = (floatx4){0.f, 0.f, 0.f, 0.f};

    for (int kk = 0; kk < 8; ++kk) {
        const int k0 = kk * 32;
        {
            int r = t >> 2, kc = t & 3;
            load_lds16(embB + (size_t)(bm0 + r) * 256 + k0 + kc * 8, &sA[t * 8]);
            load_lds16(Wpack + (size_t)(s * 256 + d0 + r) * 256 + k0 + kc * 8, &sB[t * 8]);
        }
        __syncthreads();
        bf16x8 af[4];
        #pragma unroll
        for (int mt = 0; mt < 4; ++mt)
            af[mt] = *(const bf16x8*)&sA[(mt * 16 + lrow) * 32 + q * 8];
        bf16x8 bfr = *(const bf16x8*)&sB[(w * 16 + lrow) * 32 + q * 8];
        #pragma unroll
        for (int mt = 0; mt < 4; ++mt)
            acc[mt] = __builtin_amdgcn_mfma_f32_16x16x32_bf16(af[mt], bfr, acc[mt], 0, 0, 0);
        __syncthreads();
    }

    const int d = d0 + w * 16 + lrow;
    const float bv = biasv[s * 256 + d];
    #pragma unroll
    for (int mt = 0; mt < 4; ++mt)
        #pragma unroll
        for (int rr = 0; rr < 4; ++rr) {
            int m = bm0 + mt * 16 + q * 4 + rr;
            if (m < M) preZ[(size_t)m * 1024 + s * 256 + d] = acc[mt][rr] + bv;
        }
}

// ---- launch 2: leaves (2048 blocks) + gemm_zx M=2047 (512 blocks) --------
__global__ __launch_bounds__(256) void leaves_gemm(
    const __hip_bfloat16* __restrict__ embB,
    const __hip_bfloat16* __restrict__ Wpack,
    const float* __restrict__ biasv,
    float* __restrict__ preZ,
    __hip_bfloat16* __restrict__ hbuf,
    float* __restrict__ cbuf)
{
    __shared__ __hip_bfloat16 smem[16384];   // 32 KB
    const int bid = blockIdx.x;
    if (bid < 2048) {
        // Leaves: level 15, n = 32768, start = 32767. NS=3, NP=1.
        const int n = 32768, start = n - 1;
        fused_body<3, 1>(smem, smem + 4096,
                         bid & 3, (bid >> 2) * 64,
                         embB + (size_t)start * 256, nullptr, nullptr,
                         Wpack, biasv,
                         hbuf + (size_t)start * 256, cbuf + (size_t)start * 256, n);
    } else {
        // gemm_zx for tail nodes 0..2046 (levels 10..0): 512 blocks,
        // 16 (s,d0) combos x 32 m-blocks.
        const int gid = bid - 2048;
        const int x = gid & 15;          // s*4 + d-block
        gemm_body(smem, smem + 2048,
                  x >> 2, (x & 3) * 64, (gid >> 4) * 64,
                  embB, Wpack, biasv, preZ, 2047);
    }
}

// ---- launches 3-6: big internal levels (l14..l11) ------------------------
template<int NS, int NP>
__global__ __launch_bounds__(256) void fused_level3(
    const __hip_bfloat16* __restrict__ embX,
    const __hip_bfloat16* __restrict__ hprev,
    const float* __restrict__ cprev,
    const __hip_bfloat16* __restrict__ Wpack,
    const float* __restrict__ biasv,
    __hip_bfloat16* __restrict__ hout,
    float* __restrict__ cout,
    int M)
{
    __shared__ __hip_bfloat16 sA[64 * 64];
    __shared__ __hip_bfloat16 sB[NS * 64 * 64];
    fused_body<NS, NP>(sA, sB, blockIdx.x, blockIdx.y * 64,
                       embX, hprev, cprev, Wpack, biasv, hout, cout, M);
}

// ---- tail: levels 10..0, 64 blocks x 256 threads (R10-proven) ------------
// dt = bid&15 (d-tile), g = bid>>4 (m-group 0..3); big phase (l>7): 16
// wave-slots per d-tile (slot = g*4+w, stride 16), flat 64-count barrier
// after l10,l9,l8. Levels 7..0: only g==0 blocks survive (slot = w,
// stride 4), 16-count barrier. sB XOR-swizzle both-sides (R3-proven).
__global__ __launch_bounds__(256) void tail_levels(
    __hip_bfloat16* __restrict__ hbuf, float* __restrict__ cbuf,
    const __hip_bfloat16* __restrict__ Wpack,
    const float* __restrict__ preZ,
    unsigned* __restrict__ bar, float* __restrict__ out)
{
    __shared__ __hip_bfloat16 sB[8 * 16 * 256];   // 64 KB: U mats for this d-tile
    const int bid = blockIdx.x;
    const int t = threadIdx.x;
    const int dt = bid & 15;     // d-tile
    const int g = bid >> 4;      // m-group 0..3
    const int w = t >> 6, lane = t & 63, lrow = lane & 15, q = lane >> 4;

    // Stage U mats 4..11, rows dt*16..+16, once (survives inter-level fences).
    for (int rnd = 0; rnd < 16; ++rnd) {
        int C = rnd * 256 + t;               // physical chunk 0..4095
        int q8k = C & 31, r = (C >> 5) & 15, m8 = C >> 9;
        load_lds16(Wpack + (size_t)((4 + m8) * 256 + dt * 16 + r) * 256 + (q8k ^ (r & 7)) * 8,
                   &sB[(size_t)C * 8]);
    }
    __syncthreads();

    const int d = dt * 16 + lrow;
    unsigned barnum = 0;   // big (64-count) barrier generation
    unsigned snum = 0;     // small (16-count) barrier generation

    for (int l = 10; l >= 0; --l) {
        if (l <= 7 && g != 0) break;   // 48 blocks exit after the l=8 barrier

        const int n = 1 << l;
        const int start = n - 1;
        const int startc = 2 * n - 1;
        const __hip_bfloat16* hp = hbuf + (size_t)startc * 256;
        const float* cp = cbuf + (size_t)startc * 256;
        __hip_bfloat16* ho = hbuf + (size_t)start * 256;
        float* co = cbuf + (size_t)start * 256;
        const int nmt = (n + 15) >> 4;
        const int slot   = (l > 7) ? (g * 4 + w) : w;
        const int stride = (l > 7) ? 16 : 4;

        for (int mt = slot; mt < nmt; mt += stride) {
            const int m0 = mt * 16;
            // Preload A fragments (children h): 16 independent loads.
            bf16x8 af[2][8];
            #pragma unroll
            for (int p = 0; p < 2; ++p)
                #pragma unroll
                for (int kk = 0; kk < 8; ++kk)
                    af[p][kk] = *(const bf16x8*)(hp + (size_t)(m0 + lrow) * 512 + p * 256 + kk * 32 + q * 8);
            // Preload z (bias folded) and child c.
            float zi[4][4], clr[2][4];
            #pragma unroll
            for (int rr = 0; rr < 4; ++rr) {
                int m = m0 + q * 4 + rr;
                #pragma unroll
                for (int s = 0; s < 4; ++s)
                    zi[s][rr] = preZ[(size_t)(start + m) * 1024 + s * 256 + d];
                clr[0][rr] = cp[(size_t)m * 512 + d];
                clr[1][rr] = cp[(size_t)m * 512 + 256 + d];
            }

            floatx4 accS[3], accF1, accF2;
            #pragma unroll
            for (int s = 0; s < 3; ++s)
                accS[s] = (floatx4){zi[s][0], zi[s][1], zi[s][2], zi[s][3]};
            accF1 = (floatx4){0.f, 0.f, 0.f, 0.f};
            accF2 = (floatx4){0.f, 0.f, 0.f, 0.f};

            #pragma unroll
            for (int p = 0; p < 2; ++p)
                #pragma unroll
                for (int kk = 0; kk < 8; ++kk)
                    #pragma unroll
                    for (int s = 0; s < 4; ++s) {
                        bf16x8 bfr = *(const bf16x8*)&sB[((p * 4 + s) * 16 + lrow) * 256
                                                         + (((kk * 4 + q) ^ (lrow & 7)) * 8)];
                        if (s < 3)
                            accS[s] = __builtin_amdgcn_mfma_f32_16x16x32_bf16(af[p][kk], bfr, accS[s], 0, 0, 0);
                        else if (p == 0)
                            accF1 = __builtin_amdgcn_mfma_f32_16x16x32_bf16(af[p][kk], bfr, accF1, 0, 0, 0);
                        else
                            accF2 = __builtin_amdgcn_mfma_f32_16x16x32_bf16(af[p][kk], bfr, accF2, 0, 0, 0);
                    }

            #pragma unroll
            for (int rr = 0; rr < 4; ++rr) {
                int m = m0 + q * 4 + rr;
                if (m >= n) continue;
                float iv = sigf(accS[0][rr]);
                float ov = sigf(accS[1][rr]);
                float uv = tanhf(accS[2][rr]);
                float fx = zi[3][rr];
                float fl = sigf(fx + accF1[rr]);
                float fr = sigf(fx + accF2[rr]);
                float c = iv * uv + fl * clr[0][rr] + fr * clr[1][rr];
                float hv = ov * tanhf(c);
                if (l == 0) {
                    out[d] = hv;           // root h, fp32
                    out[256 + d] = c;      // root c
                } else {
                    co[(size_t)m * 256 + d] = c;
                    ho[(size_t)m * 256 + d] = __float2bfloat16(hv);
                }
            }
        }

        if (l > 0) {
            __syncthreads();
            if (l > 7) {
                // Flat 64-count barrier (levels 10..8).
                ++barnum;
                if (t == 0) {
                    unsigned v = __hip_atomic_fetch_add(&bar[0], 1, __ATOMIC_ACQ_REL,
                                                        __HIP_MEMORY_SCOPE_AGENT) + 1;
                    if (v == barnum * 64u) {
                        __hip_atomic_fetch_add(&bar[64], 1, __ATOMIC_RELEASE,
                                               __HIP_MEMORY_SCOPE_AGENT);
                    } else {
                        while (__hip_atomic_load(&bar[64], __ATOMIC_RELAXED,
                                                 __HIP_MEMORY_SCOPE_AGENT) < barnum)
                            __builtin_amdgcn_s_sleep(1);
                    }
                }
            } else {
                // Flat 16-count barrier (levels 7..1, survivors only).
                ++snum;
                if (t == 0) {
                    unsigned v = __hip_atomic_fetch_add(&bar[128], 1, __ATOMIC_ACQ_REL,
                                                        __HIP_MEMORY_SCOPE_AGENT) + 1;
                    if (v == snum * 16u) {
                        __hip_atomic_fetch_add(&bar[192], 1, __ATOMIC_RELEASE,
                                               __HIP_MEMORY_SCOPE_AGENT);
                    } else {
                        while (__hip_atomic_load(&bar[192], __ATOMIC_RELAXED,
                                                 __HIP_MEMORY_SCOPE_AGENT) < snum)
                            __builtin_amdgcn_s_sleep(1);
                    }
                }
            }
            __syncthreads();
            __builtin_amdgcn_fence(__ATOMIC_ACQUIRE, "agent");
        }
    }
}

extern "C" void kernel_launch(void* const* d_in, const int* in_sizes, int n_in,
                              void* d_out, int out_size, void* d_ws, size_t ws_size,
                              hipStream_t stream)
{
    const float* emb = (const float*)d_in[0];
    const float* Wi  = (const float*)d_in[1];
    const float* bi  = (const float*)d_in[2];
    const float* Ui  = (const float*)d_in[3];
    const float* Wo  = (const float*)d_in[4];
    const float* bo  = (const float*)d_in[5];
    const float* Uo  = (const float*)d_in[6];
    const float* Wu  = (const float*)d_in[7];
    const float* bu  = (const float*)d_in[8];
    const float* Uu  = (const float*)d_in[9];
    const float* Wf  = (const float*)d_in[10];
    const float* bf  = (const float*)d_in[11];
    const float* Uf  = (const float*)d_in[12];

    char* p = (char*)d_ws;
    __hip_bfloat16* Wpack = (__hip_bfloat16*)p;  p += (size_t)12 * 256 * 256 * 2;
    float* biasv          = (float*)p;           p += (size_t)4 * 256 * 4;
    __hip_bfloat16* embB  = (__hip_bfloat16*)p;  p += (size_t)65535 * 256 * 2;
    __hip_bfloat16* hbuf  = (__hip_bfloat16*)p;  p += (size_t)65535 * 256 * 2;
    float* cbuf           = (float*)p;           p += (size_t)65535 * 256 * 4;
    float* preZ           = (float*)p;           p += (size_t)2047 * 1024 * 4;
    unsigned* bar         = (unsigned*)p;        p += 1024;

    // 1. setup: pack + convert + bar clear.
    setup<<<NB_PACK + NB_CONV + 1, 256, 0, stream>>>(
        Wi, bi, Ui, Wo, bo, Uo, Wu, bu, Uu, Wf, bf, Uf,
        Wpack, biasv, emb, embB, bar);

    // 2. leaves (n=32768) ∥ gemm_zx (preZ for nodes 0..2046).
    leaves_gemm<<<2560, 256, 0, stream>>>(embB, Wpack, biasv, preZ, hbuf, cbuf);

    // 3-6. big internal levels 14..11.
    for (int l = 14; l >= 11; --l) {
        const int n = 1 << l;
        const int start = n - 1;
        const int startc = 2 * n - 1;
        fused_level3<4, 3><<<dim3(4, n / 64), 256, 0, stream>>>(
            embB + (size_t)start * 256,
            hbuf + (size_t)startc * 256,
            cbuf + (size_t)startc * 256,
            Wpack, biasv,
            hbuf + (size_t)start * 256, cbuf + (size_t)start * 256, n);
    }

    // 7. tail: levels 10..0; writes root h,c to out directly.
    tail_levels<<<TB, 256, 0, stream>>>(hbuf, cbuf, Wpack, preZ, bar, (float*)d_out);
}